// Round 4
// baseline (776.106 us; speedup 1.0000x reference)
//
#include <hip/hip_runtime.h>

// GCN: 3x (linear -> symmetric-norm conv -> bias -> tanh) -> linear.
// N=200000, E=3200000, F=256->32->16->8->4, fp32.
// Round 4: CSR build via bucketed counting sort (bin -> bucket scan -> per-
// bucket LDS build). Kills fill_kernel's 205MB write-allocate traffic and
// hist_kernel's random atomics. Gathers/linears unchanged from round 3.
// Algebra: norm = dinv[s]*dinv[d]  =>  agg_i = dinv_i * (hs_i + sum_in hs_src)
// with hs = (h @ W) * dinv computed in each linear's epilogue.

constexpr int F_IN = 256;
constexpr int BSH = 7;          // bucket = dst >> 7  (128 nodes/bucket)
constexpr int BNODES = 1 << BSH;
constexpr int IMGCAP = 4608;    // LDS list image capacity (avg bucket ~2048)

// ---------------- pass A: bin edges into bucket regions ----------------
__global__ void bin_kernel(const int* __restrict__ src, const int* __restrict__ dst,
                           int* __restrict__ bcur, int2* __restrict__ pairs,
                           int CAP, int E) {
    int e = blockIdx.x * blockDim.x + threadIdx.x;
    if (e >= E) return;
    int d = dst[e];
    int b = d >> BSH;
    int pos = atomicAdd(&bcur[b], 1);
    if (pos < CAP) pairs[(size_t)b * CAP + pos] = make_int2(d, src[e]);
}

// ---------------- bucket-count exclusive scan (single block) ----------------
__global__ void scan_buckets_kernel(int* __restrict__ bcur, int* __restrict__ bbase,
                                    int NB, int CAP) {
    __shared__ int s[256];
    const int t = threadIdx.x;
    const int K = (NB + 255) / 256;       // <= 32 for N <= 1M
    int loc[32];
    int tot = 0;
    for (int i = 0; i < K; ++i) {
        int idx = t * K + i;
        int c = (idx < NB) ? min(bcur[idx], CAP) : 0;
        loc[i] = tot; tot += c;
        if (idx < NB) bcur[idx] = c;      // store clamped count back
    }
    s[t] = tot;
    int own = tot;
    __syncthreads();
    for (int off = 1; off < 256; off <<= 1) {
        int add = (t >= off) ? s[t - off] : 0; __syncthreads();
        s[t] += add; __syncthreads();
    }
    int excl = s[t] - own;
    for (int i = 0; i < K; ++i) {
        int idx = t * K + i;
        if (idx < NB) bbase[idx] = excl + loc[i];
    }
}

// ---------------- pass B: per-bucket CSR build (block = bucket) ----------------
__global__ __launch_bounds__(256) void csr_build_kernel(
        const int2* __restrict__ pairs, const int* __restrict__ bcnt,
        const int* __restrict__ bbase, int CAP,
        int* __restrict__ cnt, int* __restrict__ rowptr, float* __restrict__ dinv,
        int* __restrict__ list, int N) {
    const int b = blockIdx.x;
    const int n0 = b << BSH;
    const int t = threadIdx.x;
    __shared__ int s[256];
    __shared__ int lex[BNODES];
    __shared__ int img[IMGCAP];
    const int count = min(bcnt[b], IMGCAP);
    const int2* __restrict__ pp = pairs + (size_t)b * CAP;
    s[t] = 0; __syncthreads();
    for (int i = t; i < count; i += 256)
        atomicAdd(&s[pp[i].x - n0], 1);
    __syncthreads();
    const int own = s[t];                 // per-node degree (t<128 meaningful)
    for (int off = 1; off < 256; off <<= 1) {
        int add = (t >= off) ? s[t - off] : 0; __syncthreads();
        s[t] += add; __syncthreads();
    }
    const int excl = s[t] - own;
    if (t < BNODES) lex[t] = excl;
    const int gbase = bbase[b];
    const int n = n0 + t;
    if (t < BNODES && n < N) {
        cnt[n] = own;
        rowptr[n] = gbase + excl;
        dinv[n] = rsqrtf((float)own + 1.0f);
    }
    __syncthreads();
    s[t] = 0; __syncthreads();            // reuse as per-node cursors
    for (int i = t; i < count; i += 256) {
        int2 pr = pp[i];
        int ld = pr.x - n0;
        int p = lex[ld] + atomicAdd(&s[ld], 1);
        if (p < IMGCAP) img[p] = pr.y;
    }
    __syncthreads();
    for (int i = t; i < count; i += 256) list[gbase + i] = img[i];
}

// ---------------- layer-1 GEMM: out = (x @ W) * dinv, K=256, D=32 ----------------
__global__ __launch_bounds__(256) void linear1_kernel(const float* __restrict__ x,
                                                      const float* __restrict__ W,
                                                      const float* __restrict__ dinv,
                                                      float* __restrict__ out, int N) {
    __shared__ float Ws[F_IN * 32];      // 32 KB
    __shared__ float xs[256][17];        // 17 KB
    const int t = threadIdx.x;
    for (int i = t; i < F_IN * 32 / 4; i += 256)
        ((float4*)Ws)[i] = ((const float4*)W)[i];
    const int rg = t >> 2;               // 0..63 : row group (4 rows)
    const int cg = t & 3;                // 0..3  : col group (8 cols)
    const long row0 = (long)blockIdx.x * 256;
    float acc[4][8] = {};
    for (int kc = 0; kc < 16; ++kc) {
        for (int s = t; s < 1024; s += 256) {
            int r = s >> 2, k4 = (s & 3) * 4;
            long grow = row0 + r;
            float4 xv = make_float4(0.f, 0.f, 0.f, 0.f);
            if (grow < N) xv = *(const float4*)(x + grow * F_IN + kc * 16 + k4);
            *(float4*)&xs[r][k4] = xv;
        }
        __syncthreads();
#pragma unroll
        for (int kk = 0; kk < 16; ++kk) {
            float xv[4];
#pragma unroll
            for (int i = 0; i < 4; ++i) xv[i] = xs[rg * 4 + i][kk];
            const float4 w0 = *(const float4*)&Ws[(kc * 16 + kk) * 32 + cg * 8];
            const float4 w1 = *(const float4*)&Ws[(kc * 16 + kk) * 32 + cg * 8 + 4];
#pragma unroll
            for (int i = 0; i < 4; ++i) {
                acc[i][0] += xv[i] * w0.x; acc[i][1] += xv[i] * w0.y;
                acc[i][2] += xv[i] * w0.z; acc[i][3] += xv[i] * w0.w;
                acc[i][4] += xv[i] * w1.x; acc[i][5] += xv[i] * w1.y;
                acc[i][6] += xv[i] * w1.z; acc[i][7] += xv[i] * w1.w;
            }
        }
        __syncthreads();
    }
#pragma unroll
    for (int i = 0; i < 4; ++i) {
        long r = row0 + rg * 4 + i;
        if (r >= N) continue;
        float dv = dinv[r];
        float4 o0 = make_float4(acc[i][0] * dv, acc[i][1] * dv, acc[i][2] * dv, acc[i][3] * dv);
        float4 o1 = make_float4(acc[i][4] * dv, acc[i][5] * dv, acc[i][6] * dv, acc[i][7] * dv);
        *(float4*)(out + r * 32 + cg * 8) = o0;
        *(float4*)(out + r * 32 + cg * 8 + 4) = o1;
    }
}

// ---------------- small linear: out = (x @ W) * dinv, thread per row ----------------
template <int K, int D>
__global__ void linear_small_kernel(const float* __restrict__ x, const float* __restrict__ W,
                                    const float* __restrict__ dinv, float* __restrict__ out, int N) {
    __shared__ float Ws[K * D];
    const int t = threadIdx.x;
    for (int i = t; i < K * D; i += 256) Ws[i] = W[i];
    __syncthreads();
    long row = (long)blockIdx.x * 256 + t;
    if (row >= N) return;
    float acc[D] = {};
    const float4* xr = (const float4*)(x + row * K);
#pragma unroll
    for (int k4 = 0; k4 < K / 4; ++k4) {
        float4 xv = xr[k4];
        float xvs[4] = {xv.x, xv.y, xv.z, xv.w};
#pragma unroll
        for (int j = 0; j < 4; ++j) {
#pragma unroll
            for (int c4 = 0; c4 < D / 4; ++c4) {
                float4 w = *(const float4*)&Ws[(k4 * 4 + j) * D + c4 * 4];
                acc[c4 * 4 + 0] += xvs[j] * w.x;
                acc[c4 * 4 + 1] += xvs[j] * w.y;
                acc[c4 * 4 + 2] += xvs[j] * w.z;
                acc[c4 * 4 + 3] += xvs[j] * w.w;
            }
        }
    }
    float dv = dinv[row];
#pragma unroll
    for (int c4 = 0; c4 < D / 4; ++c4) {
        float4 o = make_float4(acc[c4 * 4 + 0] * dv, acc[c4 * 4 + 1] * dv,
                               acc[c4 * 4 + 2] * dv, acc[c4 * 4 + 3] * dv);
        *(float4*)(out + row * D + c4 * 4) = o;
    }
}

// ---------------- gather: out_i = tanh(dinv_i*(hs_i + sum hs_src) + b) ----------------
template <int D>
__global__ void gather_kernel(const int* __restrict__ rowptr, const int* __restrict__ cnt,
                              const int* __restrict__ list, const float* __restrict__ hs,
                              const float* __restrict__ dinv, const float* __restrict__ b,
                              float* __restrict__ out, int N) {
    constexpr int L = D / 4;
    constexpr int GPB = 256 / L;
    const int t = threadIdx.x;
    const int g = t / L, lane = t % L;
    long node = (long)blockIdx.x * GPB + g;
    if (node >= N) return;
    const int start = rowptr[node];
    const int num = cnt[node];
    const int* __restrict__ lp = list + start;
    const float4* __restrict__ hs4 = (const float4*)hs;
    float4 acc = hs4[node * L + lane];
    int j = 0;
    for (; j + 8 <= num; j += 8) {
        int s0 = lp[j], s1 = lp[j + 1], s2 = lp[j + 2], s3 = lp[j + 3];
        int s4 = lp[j + 4], s5 = lp[j + 5], s6 = lp[j + 6], s7 = lp[j + 7];
        float4 v0 = hs4[(long)s0 * L + lane], v1 = hs4[(long)s1 * L + lane];
        float4 v2 = hs4[(long)s2 * L + lane], v3 = hs4[(long)s3 * L + lane];
        float4 v4 = hs4[(long)s4 * L + lane], v5 = hs4[(long)s5 * L + lane];
        float4 v6 = hs4[(long)s6 * L + lane], v7 = hs4[(long)s7 * L + lane];
        acc.x += ((v0.x + v1.x) + (v2.x + v3.x)) + ((v4.x + v5.x) + (v6.x + v7.x));
        acc.y += ((v0.y + v1.y) + (v2.y + v3.y)) + ((v4.y + v5.y) + (v6.y + v7.y));
        acc.z += ((v0.z + v1.z) + (v2.z + v3.z)) + ((v4.z + v5.z) + (v6.z + v7.z));
        acc.w += ((v0.w + v1.w) + (v2.w + v3.w)) + ((v4.w + v5.w) + (v6.w + v7.w));
    }
    for (; j < num; ++j) {
        int s = lp[j];
        float4 v = hs4[(long)s * L + lane];
        acc.x += v.x; acc.y += v.y; acc.z += v.z; acc.w += v.w;
    }
    const float dv = dinv[node];
    const float4 bb = *(const float4*)(b + lane * 4);
    float4 o;
    o.x = tanhf(acc.x * dv + bb.x);
    o.y = tanhf(acc.y * dv + bb.y);
    o.z = tanhf(acc.z * dv + bb.z);
    o.w = tanhf(acc.w * dv + bb.w);
    *(float4*)(out + node * D + lane * 4) = o;
}

// ---------------- D=8 gather fused with classifier ----------------
__global__ void gather8_final_kernel(const int* __restrict__ rowptr, const int* __restrict__ cnt,
                                     const int* __restrict__ list, const float* __restrict__ hs,
                                     const float* __restrict__ dinv, const float* __restrict__ b,
                                     const float* __restrict__ Wc, const float* __restrict__ bc,
                                     float* __restrict__ out, int N) {
    const int t = threadIdx.x;
    const int g = t >> 1, lane = t & 1;
    long node = (long)blockIdx.x * 128 + g;
    if (node >= N) return;
    const int start = rowptr[node];
    const int num = cnt[node];
    const int* __restrict__ lp = list + start;
    const float4* __restrict__ hs4 = (const float4*)hs;
    float4 acc = hs4[node * 2 + lane];
    int j = 0;
    for (; j + 8 <= num; j += 8) {
        int s0 = lp[j], s1 = lp[j + 1], s2 = lp[j + 2], s3 = lp[j + 3];
        int s4 = lp[j + 4], s5 = lp[j + 5], s6 = lp[j + 6], s7 = lp[j + 7];
        float4 v0 = hs4[(long)s0 * 2 + lane], v1 = hs4[(long)s1 * 2 + lane];
        float4 v2 = hs4[(long)s2 * 2 + lane], v3 = hs4[(long)s3 * 2 + lane];
        float4 v4 = hs4[(long)s4 * 2 + lane], v5 = hs4[(long)s5 * 2 + lane];
        float4 v6 = hs4[(long)s6 * 2 + lane], v7 = hs4[(long)s7 * 2 + lane];
        acc.x += ((v0.x + v1.x) + (v2.x + v3.x)) + ((v4.x + v5.x) + (v6.x + v7.x));
        acc.y += ((v0.y + v1.y) + (v2.y + v3.y)) + ((v4.y + v5.y) + (v6.y + v7.y));
        acc.z += ((v0.z + v1.z) + (v2.z + v3.z)) + ((v4.z + v5.z) + (v6.z + v7.z));
        acc.w += ((v0.w + v1.w) + (v2.w + v3.w)) + ((v4.w + v5.w) + (v6.w + v7.w));
    }
    for (; j < num; ++j) {
        int s = lp[j];
        float4 v = hs4[(long)s * 2 + lane];
        acc.x += v.x; acc.y += v.y; acc.z += v.z; acc.w += v.w;
    }
    const float dv = dinv[node];
    const float4 bb = *(const float4*)(b + lane * 4);
    float4 h;
    h.x = tanhf(acc.x * dv + bb.x);
    h.y = tanhf(acc.y * dv + bb.y);
    h.z = tanhf(acc.z * dv + bb.z);
    h.w = tanhf(acc.w * dv + bb.w);
    const float4 w0 = *(const float4*)(Wc + (lane * 4 + 0) * 4);
    const float4 w1 = *(const float4*)(Wc + (lane * 4 + 1) * 4);
    const float4 w2 = *(const float4*)(Wc + (lane * 4 + 2) * 4);
    const float4 w3 = *(const float4*)(Wc + (lane * 4 + 3) * 4);
    float4 p;
    p.x = h.x * w0.x + h.y * w1.x + h.z * w2.x + h.w * w3.x;
    p.y = h.x * w0.y + h.y * w1.y + h.z * w2.y + h.w * w3.y;
    p.z = h.x * w0.z + h.y * w1.z + h.z * w2.z + h.w * w3.z;
    p.w = h.x * w0.w + h.y * w1.w + h.z * w2.w + h.w * w3.w;
    p.x += __shfl_xor(p.x, 1);
    p.y += __shfl_xor(p.y, 1);
    p.z += __shfl_xor(p.z, 1);
    p.w += __shfl_xor(p.w, 1);
    if (lane == 0) {
        const float4 bcv = *(const float4*)bc;
        float4 o = make_float4(p.x + bcv.x, p.y + bcv.y, p.z + bcv.z, p.w + bcv.w);
        *(float4*)(out + node * 4) = o;
    }
}

extern "C" void kernel_launch(void* const* d_in, const int* in_sizes, int n_in,
                              void* d_out, int out_size, void* d_ws, size_t ws_size,
                              hipStream_t stream) {
    const float* x  = (const float*)d_in[0];
    const int*   ei = (const int*)d_in[1];
    const float* W1 = (const float*)d_in[2];
    const float* b1 = (const float*)d_in[3];
    const float* W2 = (const float*)d_in[4];
    const float* b2 = (const float*)d_in[5];
    const float* W3 = (const float*)d_in[6];
    const float* b3 = (const float*)d_in[7];
    const float* Wc = (const float*)d_in[8];
    const float* bc = (const float*)d_in[9];
    float* out = (float*)d_out;

    const int N = in_sizes[0] / F_IN;
    const int E = in_sizes[1] / 2;
    const int* src = ei;
    const int* dst = ei + E;
    const int B = 256;

    const int NB  = (N + BNODES - 1) >> BSH;            // buckets
    const int CAP = (int)((32L * N) / NB);              // pairs slots/bucket (fits bufAB)

    char* p = (char*)d_ws;
    auto take = [&](size_t bytes) { char* q = p; p += (bytes + 255) & ~size_t(255); return q; };
    int*   cnt    = (int*)take((size_t)N * 4);
    int*   rowptr = (int*)take((size_t)N * 4);
    float* dinv   = (float*)take((size_t)N * 4);
    int*   bcur   = (int*)take((size_t)NB * 4);
    int*   bbase  = (int*)take((size_t)NB * 4);
    int*   list   = (int*)take((size_t)E * 4);
    float* bufA   = (float*)take((size_t)N * 32 * 4);
    float* bufB   = (float*)take((size_t)N * 32 * 4);
    int2*  pairs  = (int2*)bufA;   // alias: pairs dead before linear1 writes bufA

    // ---- CSR build (bucketed counting sort) ----
    hipMemsetAsync(bcur, 0, (size_t)NB * 4, stream);
    bin_kernel<<<(E + B - 1) / B, B, 0, stream>>>(src, dst, bcur, pairs, CAP, E);
    scan_buckets_kernel<<<1, B, 0, stream>>>(bcur, bbase, NB, CAP);
    csr_build_kernel<<<NB, B, 0, stream>>>(pairs, bcur, bbase, CAP, cnt, rowptr, dinv, list, N);

    // ---- layer 1: 256 -> 32 ----
    linear1_kernel<<<(N + 255) / 256, B, 0, stream>>>(x, W1, dinv, bufA, N);
    gather_kernel<32><<<(N + 31) / 32, B, 0, stream>>>(rowptr, cnt, list, bufA, dinv, b1, bufB, N);
    // ---- layer 2: 32 -> 16 ----
    linear_small_kernel<32, 16><<<(N + 255) / 256, B, 0, stream>>>(bufB, W2, dinv, bufA, N);
    gather_kernel<16><<<(N + 63) / 64, B, 0, stream>>>(rowptr, cnt, list, bufA, dinv, b2, bufB, N);
    // ---- layer 3: 16 -> 8, classifier fused ----
    linear_small_kernel<16, 8><<<(N + 255) / 256, B, 0, stream>>>(bufB, W3, dinv, bufA, N);
    gather8_final_kernel<<<(N + 127) / 128, B, 0, stream>>>(rowptr, cnt, list, bufA, dinv, b3, Wc, bc, out, N);
}

// Round 5
// 388.931 us; speedup vs baseline: 1.9955x; 1.9955x over previous
//
#include <hip/hip_runtime.h>

// GCN: 3x (linear -> symmetric-norm conv -> bias -> tanh) -> linear.
// N=200000, E=3200000, F=256->32->16->8->4, fp32.
// Round 5: CSR build as a deterministic radix-style pass: per-chunk LDS
// histograms -> per-bucket scan of [bucket][chunk] matrix (NO global atomics)
// -> LDS-cursor scatter into exact precomputed slots (single-block temporal
// locality => L2 write-combining) -> per-bucket LDS CSR build.
// Gathers/linears unchanged from round 3.
// Algebra: norm = dinv[s]*dinv[d]  =>  agg_i = dinv_i * (hs_i + sum_in hs_src)
// with hs = (h @ W) * dinv computed in each linear's epilogue.

constexpr int F_IN = 256;
constexpr int BSH = 10;            // nodes per coarse bucket = 1024
constexpr int BN  = 1 << BSH;
constexpr int CH  = 8192;          // edges per chunk

// ---- pass A1: per-chunk bucket histogram (transposed store: hist[b][c]) ----
__global__ void histc_kernel(const int* __restrict__ dst, int* __restrict__ hist,
                             int NB_C, int nch, int E) {
    __shared__ int h[256];
    const int t = threadIdx.x, c = blockIdx.x;
    h[t] = 0; __syncthreads();
    const int e0 = c * CH, e1 = min(e0 + CH, E);
    for (int e = e0 + t; e < e1; e += 256)
        atomicAdd(&h[dst[e] >> BSH], 1);
    __syncthreads();
    if (t < NB_C) hist[(size_t)t * nch + c] = h[t];
}

// ---- pass A2: exclusive scan of each bucket row (in place), total -> btotal ----
__global__ void scanb_kernel(int* __restrict__ hist, int* __restrict__ btotal, int nch) {
    __shared__ int s[256];
    const int b = blockIdx.x, t = threadIdx.x;
    int* row = hist + (size_t)b * nch;
    const int K = (nch + 255) / 256;        // <= 8 for nch <= 2048
    int loc[8]; int tot = 0;
    for (int i = 0; i < K; ++i) {
        int idx = t * K + i;
        int v = (idx < nch) ? row[idx] : 0;
        loc[i] = tot; tot += v;
    }
    s[t] = tot; const int own = tot; __syncthreads();
    for (int off = 1; off < 256; off <<= 1) {
        int a = (t >= off) ? s[t - off] : 0; __syncthreads();
        s[t] += a; __syncthreads();
    }
    const int excl = s[t] - own;
    for (int i = 0; i < K; ++i) {
        int idx = t * K + i;
        if (idx < nch) row[idx] = excl + loc[i];
    }
    if (t == 255) btotal[b] = s[255];
}

// ---- pass A3: exclusive scan of bucket totals -> colbase[NB_C+1] ----
__global__ void scanc_kernel(const int* __restrict__ btotal, int* __restrict__ colbase, int NB_C) {
    __shared__ int s[256];
    const int t = threadIdx.x;
    int v = (t < NB_C) ? btotal[t] : 0;
    s[t] = v; const int own = v; __syncthreads();
    for (int off = 1; off < 256; off <<= 1) {
        int a = (t >= off) ? s[t - off] : 0; __syncthreads();
        s[t] += a; __syncthreads();
    }
    if (t < NB_C) colbase[t] = s[t] - own;
    if (t == 255) colbase[NB_C] = s[255];
}

// ---- pass A4: scatter (dst,src) pairs to exact slots; LDS cursors only ----
__global__ void scat_kernel(const int* __restrict__ src, const int* __restrict__ dst,
                            const int* __restrict__ hist, const int* __restrict__ colbase,
                            int2* __restrict__ pairs, int NB_C, int nch, int E) {
    __shared__ int cur[256];
    const int t = threadIdx.x, c = blockIdx.x;
    if (t < NB_C) cur[t] = colbase[t] + hist[(size_t)t * nch + c];
    __syncthreads();
    const int e0 = c * CH, e1 = min(e0 + CH, E);
    for (int e = e0 + t; e < e1; e += 256) {
        int d = dst[e];
        int b = d >> BSH;
        int p = atomicAdd(&cur[b], 1);
        pairs[p] = make_int2(d, src[e]);
    }
}

// ---- pass B: per-bucket CSR build (block = 1024-node bucket) ----
__global__ __launch_bounds__(256) void csrb_kernel(const int2* __restrict__ pairs,
                                                   const int* __restrict__ colbase,
                                                   int* __restrict__ cnt, int* __restrict__ rowptr,
                                                   float* __restrict__ dinv, int* __restrict__ list,
                                                   int N) {
    __shared__ int deg[BN];
    __shared__ int lex[BN];
    __shared__ int s[256];
    const int b = blockIdx.x, t = threadIdx.x;
    const int n0 = b << BSH;
    const int g0 = colbase[b], g1 = colbase[b + 1];
    for (int i = t; i < BN; i += 256) deg[i] = 0;
    __syncthreads();
    for (int i = g0 + t; i < g1; i += 256)
        atomicAdd(&deg[pairs[i].x - n0], 1);
    __syncthreads();
    // exclusive scan of deg[1024]: thread t owns deg[4t..4t+3]
    const int b4 = t * 4;
    const int l0 = deg[b4], l1 = deg[b4 + 1], l2 = deg[b4 + 2], l3 = deg[b4 + 3];
    const int tot = l0 + l1 + l2 + l3;
    s[t] = tot; const int own = tot; __syncthreads();
    for (int off = 1; off < 256; off <<= 1) {
        int a = (t >= off) ? s[t - off] : 0; __syncthreads();
        s[t] += a; __syncthreads();
    }
    const int excl = s[t] - own;
    lex[b4] = excl; lex[b4 + 1] = excl + l0; lex[b4 + 2] = excl + l0 + l1; lex[b4 + 3] = excl + l0 + l1 + l2;
#pragma unroll
    for (int k = 0; k < 4; ++k) {
        int n = n0 + b4 + k;
        if (n < N) {
            int dg = deg[b4 + k];
            cnt[n] = dg;
            rowptr[n] = g0 + lex[b4 + k];
            dinv[n] = rsqrtf((float)dg + 1.0f);
        }
    }
    __syncthreads();
    for (int i = t; i < BN; i += 256) deg[i] = 0;   // reuse as cursors
    __syncthreads();
    for (int i = g0 + t; i < g1; i += 256) {
        int2 pr = pairs[i];
        int ld = pr.x - n0;
        int p = lex[ld] + atomicAdd(&deg[ld], 1);
        list[g0 + p] = pr.y;
    }
}

// ---------------- layer-1 GEMM: out = (x @ W) * dinv, K=256, D=32 ----------------
__global__ __launch_bounds__(256) void linear1_kernel(const float* __restrict__ x,
                                                      const float* __restrict__ W,
                                                      const float* __restrict__ dinv,
                                                      float* __restrict__ out, int N) {
    __shared__ float Ws[F_IN * 32];      // 32 KB
    __shared__ float xs[256][17];        // 17 KB
    const int t = threadIdx.x;
    for (int i = t; i < F_IN * 32 / 4; i += 256)
        ((float4*)Ws)[i] = ((const float4*)W)[i];
    const int rg = t >> 2;               // 0..63 : row group (4 rows)
    const int cg = t & 3;                // 0..3  : col group (8 cols)
    const long row0 = (long)blockIdx.x * 256;
    float acc[4][8] = {};
    for (int kc = 0; kc < 16; ++kc) {
        for (int s = t; s < 1024; s += 256) {
            int r = s >> 2, k4 = (s & 3) * 4;
            long grow = row0 + r;
            float4 xv = make_float4(0.f, 0.f, 0.f, 0.f);
            if (grow < N) xv = *(const float4*)(x + grow * F_IN + kc * 16 + k4);
            *(float4*)&xs[r][k4] = xv;
        }
        __syncthreads();
#pragma unroll
        for (int kk = 0; kk < 16; ++kk) {
            float xv[4];
#pragma unroll
            for (int i = 0; i < 4; ++i) xv[i] = xs[rg * 4 + i][kk];
            const float4 w0 = *(const float4*)&Ws[(kc * 16 + kk) * 32 + cg * 8];
            const float4 w1 = *(const float4*)&Ws[(kc * 16 + kk) * 32 + cg * 8 + 4];
#pragma unroll
            for (int i = 0; i < 4; ++i) {
                acc[i][0] += xv[i] * w0.x; acc[i][1] += xv[i] * w0.y;
                acc[i][2] += xv[i] * w0.z; acc[i][3] += xv[i] * w0.w;
                acc[i][4] += xv[i] * w1.x; acc[i][5] += xv[i] * w1.y;
                acc[i][6] += xv[i] * w1.z; acc[i][7] += xv[i] * w1.w;
            }
        }
        __syncthreads();
    }
#pragma unroll
    for (int i = 0; i < 4; ++i) {
        long r = row0 + rg * 4 + i;
        if (r >= N) continue;
        float dv = dinv[r];
        float4 o0 = make_float4(acc[i][0] * dv, acc[i][1] * dv, acc[i][2] * dv, acc[i][3] * dv);
        float4 o1 = make_float4(acc[i][4] * dv, acc[i][5] * dv, acc[i][6] * dv, acc[i][7] * dv);
        *(float4*)(out + r * 32 + cg * 8) = o0;
        *(float4*)(out + r * 32 + cg * 8 + 4) = o1;
    }
}

// ---------------- small linear: out = (x @ W) * dinv, thread per row ----------------
template <int K, int D>
__global__ void linear_small_kernel(const float* __restrict__ x, const float* __restrict__ W,
                                    const float* __restrict__ dinv, float* __restrict__ out, int N) {
    __shared__ float Ws[K * D];
    const int t = threadIdx.x;
    for (int i = t; i < K * D; i += 256) Ws[i] = W[i];
    __syncthreads();
    long row = (long)blockIdx.x * 256 + t;
    if (row >= N) return;
    float acc[D] = {};
    const float4* xr = (const float4*)(x + row * K);
#pragma unroll
    for (int k4 = 0; k4 < K / 4; ++k4) {
        float4 xv = xr[k4];
        float xvs[4] = {xv.x, xv.y, xv.z, xv.w};
#pragma unroll
        for (int j = 0; j < 4; ++j) {
#pragma unroll
            for (int c4 = 0; c4 < D / 4; ++c4) {
                float4 w = *(const float4*)&Ws[(k4 * 4 + j) * D + c4 * 4];
                acc[c4 * 4 + 0] += xvs[j] * w.x;
                acc[c4 * 4 + 1] += xvs[j] * w.y;
                acc[c4 * 4 + 2] += xvs[j] * w.z;
                acc[c4 * 4 + 3] += xvs[j] * w.w;
            }
        }
    }
    float dv = dinv[row];
#pragma unroll
    for (int c4 = 0; c4 < D / 4; ++c4) {
        float4 o = make_float4(acc[c4 * 4 + 0] * dv, acc[c4 * 4 + 1] * dv,
                               acc[c4 * 4 + 2] * dv, acc[c4 * 4 + 3] * dv);
        *(float4*)(out + row * D + c4 * 4) = o;
    }
}

// ---------------- gather: out_i = tanh(dinv_i*(hs_i + sum hs_src) + b) ----------------
template <int D>
__global__ void gather_kernel(const int* __restrict__ rowptr, const int* __restrict__ cnt,
                              const int* __restrict__ list, const float* __restrict__ hs,
                              const float* __restrict__ dinv, const float* __restrict__ b,
                              float* __restrict__ out, int N) {
    constexpr int L = D / 4;
    constexpr int GPB = 256 / L;
    const int t = threadIdx.x;
    const int g = t / L, lane = t % L;
    long node = (long)blockIdx.x * GPB + g;
    if (node >= N) return;
    const int start = rowptr[node];
    const int num = cnt[node];
    const int* __restrict__ lp = list + start;
    const float4* __restrict__ hs4 = (const float4*)hs;
    float4 acc = hs4[node * L + lane];
    int j = 0;
    for (; j + 8 <= num; j += 8) {
        int s0 = lp[j], s1 = lp[j + 1], s2 = lp[j + 2], s3 = lp[j + 3];
        int s4 = lp[j + 4], s5 = lp[j + 5], s6 = lp[j + 6], s7 = lp[j + 7];
        float4 v0 = hs4[(long)s0 * L + lane], v1 = hs4[(long)s1 * L + lane];
        float4 v2 = hs4[(long)s2 * L + lane], v3 = hs4[(long)s3 * L + lane];
        float4 v4 = hs4[(long)s4 * L + lane], v5 = hs4[(long)s5 * L + lane];
        float4 v6 = hs4[(long)s6 * L + lane], v7 = hs4[(long)s7 * L + lane];
        acc.x += ((v0.x + v1.x) + (v2.x + v3.x)) + ((v4.x + v5.x) + (v6.x + v7.x));
        acc.y += ((v0.y + v1.y) + (v2.y + v3.y)) + ((v4.y + v5.y) + (v6.y + v7.y));
        acc.z += ((v0.z + v1.z) + (v2.z + v3.z)) + ((v4.z + v5.z) + (v6.z + v7.z));
        acc.w += ((v0.w + v1.w) + (v2.w + v3.w)) + ((v4.w + v5.w) + (v6.w + v7.w));
    }
    for (; j < num; ++j) {
        int s = lp[j];
        float4 v = hs4[(long)s * L + lane];
        acc.x += v.x; acc.y += v.y; acc.z += v.z; acc.w += v.w;
    }
    const float dv = dinv[node];
    const float4 bb = *(const float4*)(b + lane * 4);
    float4 o;
    o.x = tanhf(acc.x * dv + bb.x);
    o.y = tanhf(acc.y * dv + bb.y);
    o.z = tanhf(acc.z * dv + bb.z);
    o.w = tanhf(acc.w * dv + bb.w);
    *(float4*)(out + node * D + lane * 4) = o;
}

// ---------------- D=8 gather fused with classifier ----------------
__global__ void gather8_final_kernel(const int* __restrict__ rowptr, const int* __restrict__ cnt,
                                     const int* __restrict__ list, const float* __restrict__ hs,
                                     const float* __restrict__ dinv, const float* __restrict__ b,
                                     const float* __restrict__ Wc, const float* __restrict__ bc,
                                     float* __restrict__ out, int N) {
    const int t = threadIdx.x;
    const int g = t >> 1, lane = t & 1;
    long node = (long)blockIdx.x * 128 + g;
    if (node >= N) return;
    const int start = rowptr[node];
    const int num = cnt[node];
    const int* __restrict__ lp = list + start;
    const float4* __restrict__ hs4 = (const float4*)hs;
    float4 acc = hs4[node * 2 + lane];
    int j = 0;
    for (; j + 8 <= num; j += 8) {
        int s0 = lp[j], s1 = lp[j + 1], s2 = lp[j + 2], s3 = lp[j + 3];
        int s4 = lp[j + 4], s5 = lp[j + 5], s6 = lp[j + 6], s7 = lp[j + 7];
        float4 v0 = hs4[(long)s0 * 2 + lane], v1 = hs4[(long)s1 * 2 + lane];
        float4 v2 = hs4[(long)s2 * 2 + lane], v3 = hs4[(long)s3 * 2 + lane];
        float4 v4 = hs4[(long)s4 * 2 + lane], v5 = hs4[(long)s5 * 2 + lane];
        float4 v6 = hs4[(long)s6 * 2 + lane], v7 = hs4[(long)s7 * 2 + lane];
        acc.x += ((v0.x + v1.x) + (v2.x + v3.x)) + ((v4.x + v5.x) + (v6.x + v7.x));
        acc.y += ((v0.y + v1.y) + (v2.y + v3.y)) + ((v4.y + v5.y) + (v6.y + v7.y));
        acc.z += ((v0.z + v1.z) + (v2.z + v3.z)) + ((v4.z + v5.z) + (v6.z + v7.z));
        acc.w += ((v0.w + v1.w) + (v2.w + v3.w)) + ((v4.w + v5.w) + (v6.w + v7.w));
    }
    for (; j < num; ++j) {
        int s = lp[j];
        float4 v = hs4[(long)s * 2 + lane];
        acc.x += v.x; acc.y += v.y; acc.z += v.z; acc.w += v.w;
    }
    const float dv = dinv[node];
    const float4 bb = *(const float4*)(b + lane * 4);
    float4 h;
    h.x = tanhf(acc.x * dv + bb.x);
    h.y = tanhf(acc.y * dv + bb.y);
    h.z = tanhf(acc.z * dv + bb.z);
    h.w = tanhf(acc.w * dv + bb.w);
    const float4 w0 = *(const float4*)(Wc + (lane * 4 + 0) * 4);
    const float4 w1 = *(const float4*)(Wc + (lane * 4 + 1) * 4);
    const float4 w2 = *(const float4*)(Wc + (lane * 4 + 2) * 4);
    const float4 w3 = *(const float4*)(Wc + (lane * 4 + 3) * 4);
    float4 p;
    p.x = h.x * w0.x + h.y * w1.x + h.z * w2.x + h.w * w3.x;
    p.y = h.x * w0.y + h.y * w1.y + h.z * w2.y + h.w * w3.y;
    p.z = h.x * w0.z + h.y * w1.z + h.z * w2.z + h.w * w3.z;
    p.w = h.x * w0.w + h.y * w1.w + h.z * w2.w + h.w * w3.w;
    p.x += __shfl_xor(p.x, 1);
    p.y += __shfl_xor(p.y, 1);
    p.z += __shfl_xor(p.z, 1);
    p.w += __shfl_xor(p.w, 1);
    if (lane == 0) {
        const float4 bcv = *(const float4*)bc;
        float4 o = make_float4(p.x + bcv.x, p.y + bcv.y, p.z + bcv.z, p.w + bcv.w);
        *(float4*)(out + node * 4) = o;
    }
}

extern "C" void kernel_launch(void* const* d_in, const int* in_sizes, int n_in,
                              void* d_out, int out_size, void* d_ws, size_t ws_size,
                              hipStream_t stream) {
    const float* x  = (const float*)d_in[0];
    const int*   ei = (const int*)d_in[1];
    const float* W1 = (const float*)d_in[2];
    const float* b1 = (const float*)d_in[3];
    const float* W2 = (const float*)d_in[4];
    const float* b2 = (const float*)d_in[5];
    const float* W3 = (const float*)d_in[6];
    const float* b3 = (const float*)d_in[7];
    const float* Wc = (const float*)d_in[8];
    const float* bc = (const float*)d_in[9];
    float* out = (float*)d_out;

    const int N = in_sizes[0] / F_IN;
    const int E = in_sizes[1] / 2;
    const int* src = ei;
    const int* dst = ei + E;
    const int B = 256;

    const int NB_C = (N + BN - 1) >> BSH;       // coarse buckets (196) — must be <= 256
    const int nch  = (E + CH - 1) / CH;         // chunks (391)

    char* p = (char*)d_ws;
    auto take = [&](size_t bytes) { char* q = p; p += (bytes + 255) & ~size_t(255); return q; };
    int*   cnt     = (int*)take((size_t)N * 4);
    int*   rowptr  = (int*)take((size_t)N * 4);
    float* dinv    = (float*)take((size_t)N * 4);
    int*   hist    = (int*)take((size_t)NB_C * nch * 4);   // [b][c], scanned in place
    int*   btotal  = (int*)take((size_t)NB_C * 4);
    int*   colbase = (int*)take((size_t)(NB_C + 1) * 4);
    int*   list    = (int*)take((size_t)E * 4);
    float* bufA    = (float*)take((size_t)N * 32 * 4);
    float* bufB    = (float*)take((size_t)N * 32 * 4);
    int2*  pairs   = (int2*)bufA;   // alias: pairs dead before linear1 writes bufA

    // ---- CSR build (deterministic two-level counting sort) ----
    histc_kernel<<<nch, B, 0, stream>>>(dst, hist, NB_C, nch, E);
    scanb_kernel<<<NB_C, B, 0, stream>>>(hist, btotal, nch);
    scanc_kernel<<<1, B, 0, stream>>>(btotal, colbase, NB_C);
    scat_kernel<<<nch, B, 0, stream>>>(src, dst, hist, colbase, pairs, NB_C, nch, E);
    csrb_kernel<<<NB_C, B, 0, stream>>>(pairs, colbase, cnt, rowptr, dinv, list, N);

    // ---- layer 1: 256 -> 32 ----
    linear1_kernel<<<(N + 255) / 256, B, 0, stream>>>(x, W1, dinv, bufA, N);
    gather_kernel<32><<<(N + 31) / 32, B, 0, stream>>>(rowptr, cnt, list, bufA, dinv, b1, bufB, N);
    // ---- layer 2: 32 -> 16 ----
    linear_small_kernel<32, 16><<<(N + 255) / 256, B, 0, stream>>>(bufB, W2, dinv, bufA, N);
    gather_kernel<16><<<(N + 63) / 64, B, 0, stream>>>(rowptr, cnt, list, bufA, dinv, b2, bufB, N);
    // ---- layer 3: 16 -> 8, classifier fused ----
    linear_small_kernel<16, 8><<<(N + 255) / 256, B, 0, stream>>>(bufB, W3, dinv, bufA, N);
    gather8_final_kernel<<<(N + 127) / 128, B, 0, stream>>>(rowptr, cnt, list, bufA, dinv, b3, Wc, bc, out, N);
}